// Round 1
// baseline (2248.550 us; speedup 1.0000x reference)
//
#include <hip/hip_runtime.h>
#include <math.h>

#define MINN 1e-15f

__device__ __forceinline__ float clampart(float x) {
  return fminf(fmaxf(x, -1.0f + 1e-5f), 1.0f - 1e-5f);
}
__device__ __forceinline__ float redsum(float x) {
  #pragma unroll
  for (int m = 32; m; m >>= 1) x += __shfl_xor(x, m);
  return x;
}
__device__ __forceinline__ float sigmoidf_(float x) {
  return 1.0f / (1.0f + expf(-x));
}
#define DOT4(a, b) ((a).x*(b).x + (a).y*(b).y + (a).z*(b).z + (a).w*(b).w)

// ---------------- Kernel A: per-row stats of sequence (expmap0 scalars) ----
__global__ __launch_bounds__(256) void k_stats(const float* __restrict__ seq,
    float* __restrict__ a_arr, float* __restrict__ xn_arr, float* __restrict__ art_arr) {
  int gw = (blockIdx.x * 256 + threadIdx.x) >> 6;
  int lane = threadIdx.x & 63;
  int nw = (gridDim.x * 256) >> 6;
  for (int r = gw; r < 32768; r += nw) {
    const float* row = seq + (size_t)r * 768;
    float s = 0.f;
    #pragma unroll
    for (int c = 0; c < 3; ++c) {
      float4 v = *reinterpret_cast<const float4*>(row + lane * 4 + c * 256);
      s += v.x*v.x + v.y*v.y + v.z*v.z + v.w*v.w;
    }
    s = redsum(s);
    float un  = sqrtf(s);
    float unc = fmaxf(un, MINN);
    float a   = tanhf(unc) / unc;              // proj = a * seq_row
    float xn  = fmaxf(a * un, MINN);           // ||proj|| clamped
    float art = atanhf(clampart(xn));
    if (lane == 0) { a_arr[r] = a; xn_arr[r] = xn; art_arr[r] = art; }
  }
}

// ---------------- Kernel B0: transpose U matrices into [768][384] ----------
__global__ __launch_bounds__(256) void k_transU(const float* __restrict__ uz,
    const float* __restrict__ ur, const float* __restrict__ uh, float* __restrict__ ut) {
  int idx = blockIdx.x * 256 + threadIdx.x;
  if (idx >= 768 * 384) return;
  int k = idx / 384, n = idx % 384;
  const float* U = (n < 128) ? uz : (n < 256 ? ur : uh);
  int i = n & 127;
  ut[idx] = U[(size_t)i * 768 + k];
}

// ---------------- Kernel B: f32 GEMM  MX = seq[32768x768] @ UT[768x384] ----
#define BM 128
#define BN 128
#define BKK 16
__global__ __launch_bounds__(256) void k_gemm(const float* __restrict__ A,
    const float* __restrict__ Bt, float* __restrict__ C) {
  __shared__ float As[BKK][BM];
  __shared__ float Bs[BKK][BN];
  int t = threadIdx.x;
  int m0 = blockIdx.x * BM;
  int n0 = blockIdx.y * BN;
  int tm = t & 15, tn = t >> 4;
  int arow = t >> 2, acol = (t & 3) * 4;
  int bk = t >> 4, bn = (t & 15) * 8;
  float acc[8][8];
  #pragma unroll
  for (int j = 0; j < 8; ++j)
    #pragma unroll
    for (int jj = 0; jj < 8; ++jj) acc[j][jj] = 0.f;
  for (int k0 = 0; k0 < 768; k0 += BKK) {
    float4 a0 = *reinterpret_cast<const float4*>(A + (size_t)(m0 + arow) * 768 + k0 + acol);
    float4 a1 = *reinterpret_cast<const float4*>(A + (size_t)(m0 + arow + 64) * 768 + k0 + acol);
    float4 b0 = *reinterpret_cast<const float4*>(Bt + (size_t)(k0 + bk) * 384 + n0 + bn);
    float4 b1 = *reinterpret_cast<const float4*>(Bt + (size_t)(k0 + bk) * 384 + n0 + bn + 4);
    __syncthreads();
    As[acol + 0][arow] = a0.x; As[acol + 1][arow] = a0.y;
    As[acol + 2][arow] = a0.z; As[acol + 3][arow] = a0.w;
    As[acol + 0][arow + 64] = a1.x; As[acol + 1][arow + 64] = a1.y;
    As[acol + 2][arow + 64] = a1.z; As[acol + 3][arow + 64] = a1.w;
    *reinterpret_cast<float4*>(&Bs[bk][bn]) = b0;
    *reinterpret_cast<float4*>(&Bs[bk][bn + 4]) = b1;
    __syncthreads();
    #pragma unroll
    for (int k = 0; k < BKK; ++k) {
      float af[8], bf[8];
      #pragma unroll
      for (int j = 0; j < 8; ++j) af[j] = As[k][tm + 16 * j];
      #pragma unroll
      for (int j = 0; j < 8; ++j) bf[j] = Bs[k][tn + 16 * j];
      #pragma unroll
      for (int j = 0; j < 8; ++j)
        #pragma unroll
        for (int jj = 0; jj < 8; ++jj) acc[j][jj] += af[j] * bf[jj];
    }
  }
  #pragma unroll
  for (int j = 0; j < 8; ++j)
    #pragma unroll
    for (int jj = 0; jj < 8; ++jj)
      C[(size_t)(m0 + tm + 16 * j) * 384 + n0 + tn + 16 * jj] = acc[j][jj];
}

// ---------------- Kernel B2: mobius_matvec nonlinearity per (row, gate) ----
__global__ __launch_bounds__(256) void k_mvnl(float* __restrict__ mx,
    const float* __restrict__ a_arr, const float* __restrict__ xn_arr,
    const float* __restrict__ art_arr, float* __restrict__ yn) {
  int gw = (blockIdx.x * 256 + threadIdx.x) >> 6;
  int lane = threadIdx.x & 63;
  int nw = (gridDim.x * 256) >> 6;
  for (int w = gw; w < 32768 * 3; w += nw) {
    int r = w / 3, g = w - r * 3;
    float* p = mx + (size_t)r * 384 + g * 128;
    float2 v = *reinterpret_cast<float2*>(p + lane * 2);
    float a = a_arr[r];
    float x0 = v.x * a, x1 = v.y * a;  // mx = a * raw  (proj @ U.T)
    float s = redsum(x0 * x0 + x1 * x1);
    float mxn = fmaxf(sqrtf(s), MINN);
    float xn = xn_arr[r], art = art_arr[r];
    float tt = tanhf(mxn / xn * art);
    float sc = tt / mxn;
    float2 o; o.x = x0 * sc; o.y = x1 * sc;
    *reinterpret_cast<float2*>(p + lane * 2) = o;
    if (lane == 0) yn[(size_t)r * 4 + g] = tt;   // ||result|| = tt
  }
}

// ---------------- Kernel C: sequential hyperbolic GRU scan, 1 wave per b ---
__global__ __launch_bounds__(64) void k_scan(
    const float* __restrict__ ux, const float* __restrict__ yn,
    const float* __restrict__ wz, const float* __restrict__ wr, const float* __restrict__ wh,
    const float* __restrict__ bzp, const float* __restrict__ brp, const float* __restrict__ bhp,
    const float* __restrict__ mask1, const float* __restrict__ mask2,
    float* __restrict__ uarr, float* __restrict__ varr) {
  int b = blockIdx.x;
  int l = threadIdx.x;
  __shared__ float hs[128];
  __shared__ float rs[128];
  float bz0 = bzp[l], bz1 = bzp[l + 64];
  float br0 = brp[l], br1 = brp[l + 64];
  float bh0 = bhp[l], bh1 = bhp[l + 64];
  float b2z = redsum(bz0 * bz0 + bz1 * bz1);
  float b2r = redsum(br0 * br0 + br1 * br1);
  float b2h = redsum(bh0 * bh0 + bh1 * bh1);
  float h0 = 0.f, h1 = 0.f, hn2 = 0.f;
  float acu0 = 0.f, acu1 = 0.f, acv0 = 0.f, acv1 = 0.f;
  const float* uxb = ux + (size_t)b * 128 * 384;
  const float* ynb = yn + (size_t)b * 128 * 4;
  const float* wzr0 = wz + l * 128;
  const float* wzr1 = wz + (l + 64) * 128;
  const float* wrr0 = wr + l * 128;
  const float* wrr1 = wr + (l + 64) * 128;
  const float* whr0 = wh + l * 128;
  const float* whr1 = wh + (l + 64) * 128;
  for (int t = 0; t < 128; ++t) {
    hs[l] = h0; hs[l + 64] = h1;
    __syncthreads();
    const float* uxt = uxb + t * 384;
    float uzv0 = uxt[l],       uzv1 = uxt[l + 64];
    float urv0 = uxt[128 + l], urv1 = uxt[192 + l];
    float uhv0 = uxt[256 + l], uhv1 = uxt[320 + l];
    float ynz = ynb[t * 4 + 0], ynr = ynb[t * 4 + 1], ynh = ynb[t * 4 + 2];
    float m1 = mask1[b * 128 + t], m2 = mask2[b * 128 + t];
    // ---- matvec z & r on h ----
    float mz0 = 0, mz1 = 0, mr0 = 0, mr1 = 0;
    #pragma unroll 8
    for (int jc = 0; jc < 128; jc += 4) {
      float4 hv  = *reinterpret_cast<const float4*>(&hs[jc]);
      float4 az0 = *reinterpret_cast<const float4*>(wzr0 + jc);
      float4 az1 = *reinterpret_cast<const float4*>(wzr1 + jc);
      float4 ar0 = *reinterpret_cast<const float4*>(wrr0 + jc);
      float4 ar1 = *reinterpret_cast<const float4*>(wrr1 + jc);
      mz0 += DOT4(az0, hv); mz1 += DOT4(az1, hv);
      mr0 += DOT4(ar0, hv); mr1 += DOT4(ar1, hv);
    }
    float xnh  = fmaxf(sqrtf(hn2), MINN);
    float arth = atanhf(clampart(xnh));
    float mzn2 = redsum(mz0 * mz0 + mz1 * mz1);
    float mrn2 = redsum(mr0 * mr0 + mr1 * mr1);
    float mzn = fmaxf(sqrtf(mzn2), MINN);
    float mrn = fmaxf(sqrtf(mrn2), MINN);
    float tz = tanhf(mzn / xnh * arth);
    float tr = tanhf(mrn / xnh * arth);
    float wzv0 = mz0 * (tz / mzn), wzv1 = mz1 * (tz / mzn);
    float wrv0 = mr0 * (tr / mrn), wrv1 = mr1 * (tr / mrn);
    // mobius_add(W*h~, U*x~)
    float xyz = redsum(wzv0 * uzv0 + wzv1 * uzv1);
    float xyr = redsum(wrv0 * urv0 + wrv1 * urv1);
    float az0v, az1v, ar0v, ar1v;
    { float x2 = tz * tz, y2 = ynz * ynz, xy = xyz;
      float c1 = 1.f + 2.f * xy + y2, c2 = 1.f - x2;
      float idn = 1.f / fmaxf(1.f + 2.f * xy + x2 * y2, MINN);
      az0v = (c1 * wzv0 + c2 * uzv0) * idn; az1v = (c1 * wzv1 + c2 * uzv1) * idn; }
    { float x2 = tr * tr, y2 = ynr * ynr, xy = xyr;
      float c1 = 1.f + 2.f * xy + y2, c2 = 1.f - x2;
      float idn = 1.f / fmaxf(1.f + 2.f * xy + x2 * y2, MINN);
      ar0v = (c1 * wrv0 + c2 * urv0) * idn; ar1v = (c1 * wrv1 + c2 * urv1) * idn; }
    // + bias (mobius_add)
    float az2 = redsum(az0v * az0v + az1v * az1v);
    float azb = redsum(az0v * bz0 + az1v * bz1);
    float ar2 = redsum(ar0v * ar0v + ar1v * ar1v);
    float arb = redsum(ar0v * br0 + ar1v * br1);
    float cz0, cz1, cr0, cr1;
    { float x2 = az2, y2 = b2z, xy = azb;
      float c1 = 1.f + 2.f * xy + y2, c2 = 1.f - x2;
      float idn = 1.f / fmaxf(1.f + 2.f * xy + x2 * y2, MINN);
      cz0 = (c1 * az0v + c2 * bz0) * idn; cz1 = (c1 * az1v + c2 * bz1) * idn; }
    { float x2 = ar2, y2 = b2r, xy = arb;
      float c1 = 1.f + 2.f * xy + y2, c2 = 1.f - x2;
      float idn = 1.f / fmaxf(1.f + 2.f * xy + x2 * y2, MINN);
      cr0 = (c1 * ar0v + c2 * br0) * idn; cr1 = (c1 * ar1v + c2 * br1) * idn; }
    // logmap0 -> sigmoid gates
    float cn2z = redsum(cz0 * cz0 + cz1 * cz1);
    float cn2r = redsum(cr0 * cr0 + cr1 * cr1);
    float cnz = fmaxf(sqrtf(cn2z), MINN);
    float cnr = fmaxf(sqrtf(cn2r), MINN);
    float lsz = atanhf(clampart(cnz)) / cnz;
    float lsr = atanhf(clampart(cnr)) / cnr;
    float zg0 = sigmoidf_(lsz * cz0), zg1 = sigmoidf_(lsz * cz1);
    float rg0 = sigmoidf_(lsr * cr0), rg1 = sigmoidf_(lsr * cr1);
    // rh = mobius_pointwise_mul(h, r)
    float p0 = h0 * rg0, p1 = h1 * rg1;
    float pn2 = redsum(p0 * p0 + p1 * p1);
    float pn = fmaxf(sqrtf(pn2), MINN);
    float trh = tanhf(pn / xnh * arth);
    float rt0 = p0 * (trh / pn), rt1 = p1 * (trh / pn);
    rs[l] = rt0; rs[l + 64] = rt1;
    __syncthreads();
    // ---- matvec h on rh ----
    float mh0 = 0, mh1 = 0;
    #pragma unroll 8
    for (int jc = 0; jc < 128; jc += 4) {
      float4 hv  = *reinterpret_cast<const float4*>(&rs[jc]);
      float4 ah0 = *reinterpret_cast<const float4*>(whr0 + jc);
      float4 ah1 = *reinterpret_cast<const float4*>(whr1 + jc);
      mh0 += DOT4(ah0, hv); mh1 += DOT4(ah1, hv);
    }
    float xnp = fmaxf(trh, MINN);               // ||rh|| = trh
    float mhn2 = redsum(mh0 * mh0 + mh1 * mh1);
    float mhn = fmaxf(sqrtf(mhn2), MINN);
    float th = tanhf(mhn / xnp * atanhf(clampart(xnp)));
    float whv0 = mh0 * (th / mhn), whv1 = mh1 * (th / mhn);
    float xyh = redsum(whv0 * uhv0 + whv1 * uhv1);
    float ah0v, ah1v;
    { float x2 = th * th, y2 = ynh * ynh, xy = xyh;
      float c1 = 1.f + 2.f * xy + y2, c2 = 1.f - x2;
      float idn = 1.f / fmaxf(1.f + 2.f * xy + x2 * y2, MINN);
      ah0v = (c1 * whv0 + c2 * uhv0) * idn; ah1v = (c1 * whv1 + c2 * uhv1) * idn; }
    float ah2 = redsum(ah0v * ah0v + ah1v * ah1v);
    float ahb = redsum(ah0v * bh0 + ah1v * bh1);
    float ct0, ct1;
    { float x2 = ah2, y2 = b2h, xy = ahb;
      float c1 = 1.f + 2.f * xy + y2, c2 = 1.f - x2;
      float idn = 1.f / fmaxf(1.f + 2.f * xy + x2 * y2, MINN);
      ct0 = (c1 * ah0v + c2 * bh0) * idn; ct1 = (c1 * ah1v + c2 * bh1) * idn; }
    // delta = mobius_add(-h, h_tilde)
    float ct2 = redsum(ct0 * ct0 + ct1 * ct1);
    float hct = redsum(h0 * ct0 + h1 * ct1);
    float dl0, dl1;
    { float x2 = hn2, y2 = ct2, xy = -hct;
      float c1 = 1.f + 2.f * xy + y2, c2 = 1.f - x2;
      float idn = 1.f / fmaxf(1.f + 2.f * xy + x2 * y2, MINN);
      dl0 = (c1 * (-h0) + c2 * ct0) * idn; dl1 = (c1 * (-h1) + c2 * ct1) * idn; }
    // zdelta = mobius_pointwise_mul(delta, z)
    float dn2 = redsum(dl0 * dl0 + dl1 * dl1);
    float w0 = dl0 * zg0, w1 = dl1 * zg1;
    float wn2 = redsum(w0 * w0 + w1 * w1);
    float dn = fmaxf(sqrtf(dn2), MINN);
    float wn = fmaxf(sqrtf(wn2), MINN);
    float tdd = tanhf(wn / dn * atanhf(clampart(dn)));
    float zd0 = w0 * (tdd / wn), zd1 = w1 * (tdd / wn);
    // h_new = mobius_add(h, zdelta)
    float hzd = redsum(h0 * zd0 + h1 * zd1);
    { float x2 = hn2, y2 = tdd * tdd, xy = hzd;
      float c1 = 1.f + 2.f * xy + y2, c2 = 1.f - x2;
      float idn = 1.f / fmaxf(1.f + 2.f * xy + x2 * y2, MINN);
      float nh0 = (c1 * h0 + c2 * zd0) * idn;
      float nh1 = (c1 * h1 + c2 * zd1) * idn;
      h0 = nh0; h1 = nh1; }
    hn2 = redsum(h0 * h0 + h1 * h1);
    acu0 += m1 * h0; acu1 += m1 * h1;
    acv0 += m2 * h0; acv1 += m2 * h1;
  }
  uarr[b * 128 + l] = acu0; uarr[b * 128 + 64 + l] = acu1;
  varr[b * 128 + l] = acv0; varr[b * 128 + 64 + l] = acv1;
}

// ---------------- Kernel D: dist + mobius FF + hyperbolic MLR, 1 wave/b ----
__global__ __launch_bounds__(64) void k_final(
    const float* __restrict__ uarr, const float* __restrict__ varr,
    const float* __restrict__ wfu, const float* __restrict__ wfv,
    const float* __restrict__ bff, const float* __restrict__ bffd,
    const float* __restrict__ wfc, const float* __restrict__ pmlr,
    const float* __restrict__ amlr, const int* __restrict__ cids,
    const float* __restrict__ csemb, float* __restrict__ out) {
  int b = blockIdx.x;
  int l = threadIdx.x;
  __shared__ float us[128], vs[128], cbuf[64];
  float q0 = uarr[b * 128 + l], q1 = uarr[b * 128 + 64 + l];
  float r0 = varr[b * 128 + l], r1 = varr[b * 128 + 64 + l];
  us[l] = q0; us[l + 64] = q1; vs[l] = r0; vs[l + 64] = r1;
  __syncthreads();
  float u2 = redsum(q0 * q0 + q1 * q1);
  float v2 = redsum(r0 * r0 + r1 * r1);
  float uv = redsum(q0 * r0 + q1 * r1);
  // dist(u,v)
  float dsq;
  { float x2 = u2, y2 = v2, xy = -uv;
    float c1 = 1.f + 2.f * xy + y2, c2 = 1.f - x2;
    float idn = 1.f / fmaxf(1.f + 2.f * xy + x2 * y2, MINN);
    float d0 = (c1 * (-q0) + c2 * r0) * idn, d1 = (c1 * (-q1) + c2 * r1) * idn;
    float dn2 = redsum(d0 * d0 + d1 * d1);
    dsq = 2.f * atanhf(clampart(sqrtf(dn2))); }
  // mobius_matvec(W_ff_u, u) and (W_ff_v, v): out dim 64, lane l = row l
  float mxu = 0.f, mxv = 0.f;
  #pragma unroll 4
  for (int jc = 0; jc < 128; jc += 4) {
    float4 uu = *reinterpret_cast<const float4*>(&us[jc]);
    float4 vv = *reinterpret_cast<const float4*>(&vs[jc]);
    float4 wu4 = *reinterpret_cast<const float4*>(wfu + (size_t)l * 128 + jc);
    float4 wv4 = *reinterpret_cast<const float4*>(wfv + (size_t)l * 128 + jc);
    mxu += DOT4(wu4, uu); mxv += DOT4(wv4, vv);
  }
  float xnu = fmaxf(sqrtf(u2), MINN);
  float xnv = fmaxf(sqrtf(v2), MINN);
  float mun = fmaxf(sqrtf(redsum(mxu * mxu)), MINN);
  float mvn = fmaxf(sqrtf(redsum(mxv * mxv)), MINN);
  float tu = tanhf(mun / xnu * atanhf(clampart(xnu)));
  float tv = tanhf(mvn / xnv * atanhf(clampart(xnv)));
  float fu = mxu * (tu / mun), fv = mxv * (tv / mvn);
  // out = mobius_add(fu, fv)
  float o1;
  { float x2 = tu * tu, y2 = tv * tv, xy = redsum(fu * fv);
    float c1 = 1.f + 2.f * xy + y2, c2 = 1.f - x2;
    float idn = 1.f / fmaxf(1.f + 2.f * xy + x2 * y2, MINN);
    o1 = (c1 * fu + c2 * fv) * idn; }
  // out = mobius_add(out, b_ff)
  float bffl = bff[l];
  float bf2 = redsum(bffl * bffl);
  float o2;
  { float x2 = redsum(o1 * o1), y2 = bf2, xy = redsum(o1 * bffl);
    float c1 = 1.f + 2.f * xy + y2, c2 = 1.f - x2;
    float idn = 1.f / fmaxf(1.f + 2.f * xy + x2 * y2, MINN);
    o2 = (c1 * o1 + c2 * bffl) * idn; }
  // mobius_scalar_mul(dsq, b_ff_d)
  float bdl = bffd[l];
  float bdn = fmaxf(sqrtf(redsum(bdl * bdl)), MINN);
  float tsm = tanhf(dsq * atanhf(clampart(bdn)));
  float sm = bdl * (tsm / bdn);
  float o3;
  { float x2 = redsum(o2 * o2), y2 = tsm * tsm, xy = redsum(o2 * sm);
    float c1 = 1.f + 2.f * xy + y2, c2 = 1.f - x2;
    float idn = 1.f / fmaxf(1.f + 2.f * xy + x2 * y2, MINN);
    o3 = (c1 * o2 + c2 * sm) * idn; }
  // mobius_matvec(W_ff_common, common)
  int cid = cids[b];
  float ce = csemb[(size_t)cid * 64 + l];
  cbuf[l] = ce;
  __syncthreads();
  float ce2 = redsum(ce * ce);
  float mxc = 0.f;
  #pragma unroll 4
  for (int jc = 0; jc < 64; jc += 4) {
    float4 cc = *reinterpret_cast<const float4*>(&cbuf[jc]);
    float4 wc4 = *reinterpret_cast<const float4*>(wfc + (size_t)l * 64 + jc);
    mxc += DOT4(wc4, cc);
  }
  float xnc = fmaxf(sqrtf(ce2), MINN);
  float mcn = fmaxf(sqrtf(redsum(mxc * mxc)), MINN);
  float tc = tanhf(mcn / xnc * atanhf(clampart(xnc)));
  float fc = mxc * (tc / mcn);
  float o4;
  { float x2 = redsum(o3 * o3), y2 = tc * tc, xy = redsum(o3 * fc);
    float c1 = 1.f + 2.f * xy + y2, c2 = 1.f - x2;
    float idn = 1.f / fmaxf(1.f + 2.f * xy + x2 * y2, MINN);
    o4 = (c1 * o3 + c2 * fc) * idn; }
  // logmap0 then expmap0
  float on = fmaxf(sqrtf(redsum(o4 * o4)), MINN);
  float lo = o4 * (atanhf(clampart(on)) / on);
  float un = fmaxf(sqrtf(redsum(lo * lo)), MINN);
  float eo = lo * (tanhf(un) / un);
  float eo2 = redsum(eo * eo);
  // hyperbolic MLR
  for (int c = 0; c < 4; ++c) {
    float pc = pmlr[c * 64 + l];
    float ac = amlr[c * 64 + l];
    float p2 = redsum(pc * pc);
    float pe = redsum(pc * eo);
    float x2 = p2, y2 = eo2, xy = -pe;
    float c1 = 1.f + 2.f * xy + y2, c2 = 1.f - x2;
    float idn = 1.f / fmaxf(1.f + 2.f * xy + x2 * y2, MINN);
    float mp = (c1 * (-pc) + c2 * eo) * idn;
    float mp2 = redsum(mp * mp);
    float lam = 2.f / (1.f - mp2);
    float na = sqrtf(redsum(ac * ac));
    float au = ac / fmaxf(na, 1e-12f);
    float pda = redsum(mp * au);
    if (l == 0) out[b * 4 + c] = 2.f * na * asinhf(pda * lam);
  }
}

extern "C" void kernel_launch(void* const* d_in, const int* in_sizes, int n_in,
                              void* d_out, int out_size, void* d_ws, size_t ws_size,
                              hipStream_t stream) {
  const float* seq   = (const float*)d_in[0];
  const float* mask1 = (const float*)d_in[1];
  const float* mask2 = (const float*)d_in[2];
  const int*   cids  = (const int*)d_in[3];
  const float* csemb = (const float*)d_in[4];
  const float* wz  = (const float*)d_in[5];
  const float* wr  = (const float*)d_in[6];
  const float* wh  = (const float*)d_in[7];
  const float* uz  = (const float*)d_in[8];
  const float* ur  = (const float*)d_in[9];
  const float* uh  = (const float*)d_in[10];
  const float* bz  = (const float*)d_in[11];
  const float* br  = (const float*)d_in[12];
  const float* bh  = (const float*)d_in[13];
  const float* wfu = (const float*)d_in[14];
  const float* wfv = (const float*)d_in[15];
  const float* bff = (const float*)d_in[16];
  const float* bffd= (const float*)d_in[17];
  const float* wfc = (const float*)d_in[18];
  const float* pmlr= (const float*)d_in[19];
  const float* amlr= (const float*)d_in[20];
  float* ws = (float*)d_ws;
  float* mx      = ws;                             // 32768*384
  float* a_arr   = mx + (size_t)32768 * 384;       // 32768
  float* xn_arr  = a_arr + 32768;                  // 32768
  float* art_arr = xn_arr + 32768;                 // 32768
  float* yn      = art_arr + 32768;                // 32768*4
  float* ut      = yn + (size_t)32768 * 4;         // 768*384
  float* uarr    = ut + 768 * 384;                 // 256*128
  float* varr    = uarr + 256 * 128;               // 256*128

  k_stats<<<dim3(2048), dim3(256), 0, stream>>>(seq, a_arr, xn_arr, art_arr);
  k_transU<<<dim3(1152), dim3(256), 0, stream>>>(uz, ur, uh, ut);
  k_gemm<<<dim3(256, 3), dim3(256), 0, stream>>>(seq, ut, mx);
  k_mvnl<<<dim3(4096), dim3(256), 0, stream>>>(mx, a_arr, xn_arr, art_arr, yn);
  k_scan<<<dim3(256), dim3(64), 0, stream>>>(mx, yn, wz, wr, wh, bz, br, bh,
                                             mask1, mask2, uarr, varr);
  k_final<<<dim3(256), dim3(64), 0, stream>>>(uarr, varr, wfu, wfv, bff, bffd,
                                              wfc, pmlr, amlr, cids, csemb,
                                              (float*)d_out);
}

// Round 2
// 1748.507 us; speedup vs baseline: 1.2860x; 1.2860x over previous
//
#include <hip/hip_runtime.h>
#include <math.h>

#define MINN 1e-15f
#define ONE_EPS 0.99999f   // 1 - 1e-5 (artanh clamp)

__device__ __forceinline__ float clampart(float x) {
  return fminf(fmaxf(x, -1.0f + 1e-5f), 1.0f - 1e-5f);
}
__device__ __forceinline__ float redsum(float x) {
  #pragma unroll
  for (int m = 32; m; m >>= 1) x += __shfl_xor(x, m);
  return x;
}
__device__ __forceinline__ float frcp(float x) { return __builtin_amdgcn_rcpf(x); }
__device__ __forceinline__ float fexp2(float x) { return __builtin_amdgcn_exp2f(x); }
__device__ __forceinline__ float flog2(float x) { return __builtin_amdgcn_logf(x); }
// x >= 0
__device__ __forceinline__ float ftanh(float x) {
  float e = fexp2(x * 2.88539008f);          // exp(2x)
  return 1.0f - 2.0f * frcp(e + 1.0f);
}
// 0 <= x < 1
__device__ __forceinline__ float fatanh(float x) {
  return 0.34657359f * flog2((1.0f + x) * frcp(1.0f - x));
}
__device__ __forceinline__ float fsig(float x) {
  return frcp(1.0f + fexp2(-1.44269504f * x));
}
__device__ __forceinline__ float sigmoidf_(float x) { return fsig(x); }
#define DOT4(a, b) ((a).x*(b).x + (a).y*(b).y + (a).z*(b).z + (a).w*(b).w)

// ---------------- Kernel A: per-row stats of sequence (expmap0 scalars) ----
__global__ __launch_bounds__(256) void k_stats(const float* __restrict__ seq,
    float* __restrict__ a_arr, float* __restrict__ xn_arr, float* __restrict__ art_arr) {
  int gw = (blockIdx.x * 256 + threadIdx.x) >> 6;
  int lane = threadIdx.x & 63;
  int nw = (gridDim.x * 256) >> 6;
  for (int r = gw; r < 32768; r += nw) {
    const float* row = seq + (size_t)r * 768;
    float s = 0.f;
    #pragma unroll
    for (int c = 0; c < 3; ++c) {
      float4 v = *reinterpret_cast<const float4*>(row + lane * 4 + c * 256);
      s += v.x*v.x + v.y*v.y + v.z*v.z + v.w*v.w;
    }
    s = redsum(s);
    float un  = sqrtf(s);
    float unc = fmaxf(un, MINN);
    float a   = tanhf(unc) / unc;              // proj = a * seq_row
    float xn  = fmaxf(a * un, MINN);           // ||proj|| clamped
    float art = atanhf(clampart(xn));
    if (lane == 0) { a_arr[r] = a; xn_arr[r] = xn; art_arr[r] = art; }
  }
}

// ---------------- Kernel B0: transpose U matrices into [768][384] ----------
__global__ __launch_bounds__(256) void k_transU(const float* __restrict__ uz,
    const float* __restrict__ ur, const float* __restrict__ uh, float* __restrict__ ut) {
  int idx = blockIdx.x * 256 + threadIdx.x;
  if (idx >= 768 * 384) return;
  int k = idx / 384, n = idx % 384;
  const float* U = (n < 128) ? uz : (n < 256 ? ur : uh);
  int i = n & 127;
  ut[idx] = U[(size_t)i * 768 + k];
}

// ---------------- Kernel B: f32 GEMM  MX = seq[32768x768] @ UT[768x384] ----
#define BM 128
#define BN 128
#define BKK 16
__global__ __launch_bounds__(256) void k_gemm(const float* __restrict__ A,
    const float* __restrict__ Bt, float* __restrict__ C) {
  __shared__ float As[BKK][BM];
  __shared__ float Bs[BKK][BN];
  int t = threadIdx.x;
  int m0 = blockIdx.x * BM;
  int n0 = blockIdx.y * BN;
  int tm = t & 15, tn = t >> 4;
  int arow = t >> 2, acol = (t & 3) * 4;
  int bk = t >> 4, bn = (t & 15) * 8;
  float acc[8][8];
  #pragma unroll
  for (int j = 0; j < 8; ++j)
    #pragma unroll
    for (int jj = 0; jj < 8; ++jj) acc[j][jj] = 0.f;
  for (int k0 = 0; k0 < 768; k0 += BKK) {
    float4 a0 = *reinterpret_cast<const float4*>(A + (size_t)(m0 + arow) * 768 + k0 + acol);
    float4 a1 = *reinterpret_cast<const float4*>(A + (size_t)(m0 + arow + 64) * 768 + k0 + acol);
    float4 b0 = *reinterpret_cast<const float4*>(Bt + (size_t)(k0 + bk) * 384 + n0 + bn);
    float4 b1 = *reinterpret_cast<const float4*>(Bt + (size_t)(k0 + bk) * 384 + n0 + bn + 4);
    __syncthreads();
    As[acol + 0][arow] = a0.x; As[acol + 1][arow] = a0.y;
    As[acol + 2][arow] = a0.z; As[acol + 3][arow] = a0.w;
    As[acol + 0][arow + 64] = a1.x; As[acol + 1][arow + 64] = a1.y;
    As[acol + 2][arow + 64] = a1.z; As[acol + 3][arow + 64] = a1.w;
    *reinterpret_cast<float4*>(&Bs[bk][bn]) = b0;
    *reinterpret_cast<float4*>(&Bs[bk][bn + 4]) = b1;
    __syncthreads();
    #pragma unroll
    for (int k = 0; k < BKK; ++k) {
      float af[8], bf[8];
      #pragma unroll
      for (int j = 0; j < 8; ++j) af[j] = As[k][tm + 16 * j];
      #pragma unroll
      for (int j = 0; j < 8; ++j) bf[j] = Bs[k][tn + 16 * j];
      #pragma unroll
      for (int j = 0; j < 8; ++j)
        #pragma unroll
        for (int jj = 0; jj < 8; ++jj) acc[j][jj] += af[j] * bf[jj];
    }
  }
  #pragma unroll
  for (int j = 0; j < 8; ++j)
    #pragma unroll
    for (int jj = 0; jj < 8; ++jj)
      C[(size_t)(m0 + tm + 16 * j) * 384 + n0 + tn + 16 * jj] = acc[j][jj];
}

// ---------------- Kernel B2: mobius_matvec nonlinearity per (row, gate) ----
__global__ __launch_bounds__(256) void k_mvnl(float* __restrict__ mx,
    const float* __restrict__ a_arr, const float* __restrict__ xn_arr,
    const float* __restrict__ art_arr, float* __restrict__ yn) {
  int gw = (blockIdx.x * 256 + threadIdx.x) >> 6;
  int lane = threadIdx.x & 63;
  int nw = (gridDim.x * 256) >> 6;
  for (int w = gw; w < 32768 * 3; w += nw) {
    int r = w / 3, g = w - r * 3;
    float* p = mx + (size_t)r * 384 + g * 128;
    float2 v = *reinterpret_cast<float2*>(p + lane * 2);
    float a = a_arr[r];
    float x0 = v.x * a, x1 = v.y * a;  // mx = a * raw  (proj @ U.T)
    float s = redsum(x0 * x0 + x1 * x1);
    float mxn = fmaxf(sqrtf(s), MINN);
    float xn = xn_arr[r], art = art_arr[r];
    float tt = tanhf(mxn / xn * art);
    float sc = tt / mxn;
    float2 o; o.x = x0 * sc; o.y = x1 * sc;
    *reinterpret_cast<float2*>(p + lane * 2) = o;
    if (lane == 0) yn[(size_t)r * 4 + g] = tt;   // ||result|| = tt
  }
}

// ---------------- Kernel C: sequential hyperbolic GRU scan, 1 wave per b ---
// wz, wr staged in swizzled LDS (128KB); wh rows held in VGPRs (256 regs).
// All mobius_add output norms computed analytically; reductions batched into
// 3 parallel butterfly windows per step.
__global__ __launch_bounds__(64) void k_scan(
    const float* __restrict__ ux, const float* __restrict__ yn,
    const float* __restrict__ wz, const float* __restrict__ wr, const float* __restrict__ wh,
    const float* __restrict__ bzp, const float* __restrict__ brp, const float* __restrict__ bhp,
    const float* __restrict__ mask1, const float* __restrict__ mask2,
    float* __restrict__ uarr, float* __restrict__ varr) {
  extern __shared__ __align__(16) float lds[];
  float4* wzs4 = (float4*)lds;            // 4096 float4 = 64KB
  float4* wrs4 = wzs4 + 4096;             // 64KB
  float*  hs   = (float*)(wrs4 + 4096);   // 128 floats
  float*  rs   = hs + 128;                // 128 floats
  float4* hs4  = (float4*)hs;
  float4* rs4  = (float4*)rs;

  int b = blockIdx.x, l = threadIdx.x;
  int sl = l & 31;

  // ---- stage wz, wr into LDS with 32-slot XOR swizzle (bank-balanced) ----
  const float4* wzg = (const float4*)wz;
  const float4* wrg = (const float4*)wr;
  for (int i = l; i < 4096; i += 64) {
    int r = i >> 5, c = i & 31;
    int d = (r << 5) | (c ^ (r & 31));
    wzs4[d] = wzg[i];
    wrs4[d] = wrg[i];
  }
  // ---- wh rows l and l+64 into registers (statically indexed) ----
  const float4* whg = (const float4*)wh;
  float4 whA[32], whB[32];
  #pragma unroll
  for (int j = 0; j < 32; ++j) whA[j] = whg[l * 32 + j];
  #pragma unroll
  for (int j = 0; j < 32; ++j) whB[j] = whg[(l + 64) * 32 + j];

  float bz0 = bzp[l], bz1 = bzp[l + 64];
  float br0 = brp[l], br1 = brp[l + 64];
  float bh0 = bhp[l], bh1 = bhp[l + 64];
  float b2z = redsum(bz0 * bz0 + bz1 * bz1);
  float b2r = redsum(br0 * br0 + br1 * br1);
  float b2h = redsum(bh0 * bh0 + bh1 * bh1);

  float h0 = 0.f, h1 = 0.f, hn2 = 0.f;
  float au0 = 0.f, au1 = 0.f, av0 = 0.f, av1 = 0.f;
  const float*  uxb  = ux + (size_t)b * 128 * 384;
  const float4* ynb4 = (const float4*)yn + (size_t)b * 128;
  const float*  m1p  = mask1 + b * 128;
  const float*  m2p  = mask2 + b * 128;
  __syncthreads();

  for (int t = 0; t < 128; ++t) {
    hs[l] = h0; hs[l + 64] = h1;
    __syncthreads();
    // early loads for this step (consumed after matvec+window A)
    const float* uxt = uxb + t * 384;
    float uz0 = uxt[l],       uz1 = uxt[l + 64];
    float ur0 = uxt[128 + l], ur1 = uxt[192 + l];
    float uh0 = uxt[256 + l], uh1 = uxt[320 + l];
    float4 ynt = ynb4[t];
    float m1 = m1p[t], m2 = m2p[t];

    // ---- z/r matvec from LDS ----
    float mz0 = 0.f, mz1 = 0.f, mr0 = 0.f, mr1 = 0.f;
    #pragma unroll
    for (int jc = 0; jc < 32; ++jc) {
      float4 hv = hs4[jc];
      int slot = jc ^ sl;
      float4 a0 = wzs4[(l << 5) | slot];
      float4 a1 = wzs4[((l + 64) << 5) | slot];
      float4 c0 = wrs4[(l << 5) | slot];
      float4 c1 = wrs4[((l + 64) << 5) | slot];
      mz0 += DOT4(a0, hv); mz1 += DOT4(a1, hv);
      mr0 += DOT4(c0, hv); mr1 += DOT4(c1, hv);
    }
    // ---- reduction window A: 8 independent butterflies ----
    float sMz2  = redsum(mz0 * mz0 + mz1 * mz1);
    float sMr2  = redsum(mr0 * mr0 + mr1 * mr1);
    float sMzUz = redsum(mz0 * uz0 + mz1 * uz1);
    float sMrUr = redsum(mr0 * ur0 + mr1 * ur1);
    float sMzBz = redsum(mz0 * bz0 + mz1 * bz1);
    float sMrBr = redsum(mr0 * br0 + mr1 * br1);
    float sUzBz = redsum(uz0 * bz0 + uz1 * bz1);
    float sUrBr = redsum(ur0 * br0 + ur1 * br1);

    float xnh  = fmaxf(sqrtf(hn2), MINN);
    float arth = fatanh(fminf(xnh, ONE_EPS));
    float axr  = arth * frcp(xnh);          // artanh(||h||)/||h||
    float ynz = ynt.x, ynr = ynt.y, ynh = ynt.z;

    // ---- z chain (scalar, analytic norms) ----
    float mzn = fmaxf(sqrtf(sMz2), MINN);
    float tz  = ftanh(mzn * axr);
    float szs = tz * frcp(mzn);
    float xyz = szs * sMzUz;
    float y2z = ynz * ynz, x2z = tz * tz;
    float c1z = 1.f + 2.f * xyz + y2z, c2z = 1.f - x2z;
    float idnz = frcp(fmaxf(1.f + 2.f * xyz + x2z * y2z, MINN));
    float az0 = (c1z * szs * mz0 + c2z * uz0) * idnz;
    float az1 = (c1z * szs * mz1 + c2z * uz1) * idnz;
    float az2 = fmaxf(idnz * idnz * (c1z * c1z * x2z + 2.f * c1z * c2z * xyz + c2z * c2z * y2z), 0.f);
    float azb = idnz * (c1z * szs * sMzBz + c2z * sUzBz);
    float c1zb = 1.f + 2.f * azb + b2z, c2zb = 1.f - az2;
    float idnzb = frcp(fmaxf(1.f + 2.f * azb + az2 * b2z, MINN));
    float cz0 = (c1zb * az0 + c2zb * bz0) * idnzb;
    float cz1 = (c1zb * az1 + c2zb * bz1) * idnzb;
    float cn2z = fmaxf(idnzb * idnzb * (c1zb * c1zb * az2 + 2.f * c1zb * c2zb * azb + c2zb * c2zb * b2z), 0.f);
    float cnz = fmaxf(sqrtf(cn2z), MINN);
    float lsz = fatanh(fminf(cnz, ONE_EPS)) * frcp(cnz);
    float zg0 = fsig(lsz * cz0), zg1 = fsig(lsz * cz1);

    // ---- r chain ----
    float mrn = fmaxf(sqrtf(sMr2), MINN);
    float trr = ftanh(mrn * axr);
    float srs = trr * frcp(mrn);
    float xyr = srs * sMrUr;
    float y2r = ynr * ynr, x2r = trr * trr;
    float c1r = 1.f + 2.f * xyr + y2r, c2r = 1.f - x2r;
    float idnr = frcp(fmaxf(1.f + 2.f * xyr + x2r * y2r, MINN));
    float ar0 = (c1r * srs * mr0 + c2r * ur0) * idnr;
    float ar1 = (c1r * srs * mr1 + c2r * ur1) * idnr;
    float ar2 = fmaxf(idnr * idnr * (c1r * c1r * x2r + 2.f * c1r * c2r * xyr + c2r * c2r * y2r), 0.f);
    float arb = idnr * (c1r * srs * sMrBr + c2r * sUrBr);
    float c1rb = 1.f + 2.f * arb + b2r, c2rb = 1.f - ar2;
    float idnrb = frcp(fmaxf(1.f + 2.f * arb + ar2 * b2r, MINN));
    float cr0 = (c1rb * ar0 + c2rb * br0) * idnrb;
    float cr1 = (c1rb * ar1 + c2rb * br1) * idnrb;
    float cn2r = fmaxf(idnrb * idnrb * (c1rb * c1rb * ar2 + 2.f * c1rb * c2rb * arb + c2rb * c2rb * b2r), 0.f);
    float cnr = fmaxf(sqrtf(cn2r), MINN);
    float lsr = fatanh(fminf(cnr, ONE_EPS)) * frcp(cnr);
    float rg0 = fsig(lsr * cr0), rg1 = fsig(lsr * cr1);

    // ---- rh = mobius_pointwise_mul(h, r) ----
    float p0 = h0 * rg0, p1 = h1 * rg1;
    float pn2 = redsum(p0 * p0 + p1 * p1);
    float pn = fmaxf(sqrtf(pn2), MINN);
    float trh = ftanh(pn * axr);
    float srt = trh * frcp(pn);
    rs[l] = p0 * srt; rs[l + 64] = p1 * srt;
    __syncthreads();

    // ---- h matvec from registers ----
    float mh0 = 0.f, mh1 = 0.f;
    #pragma unroll
    for (int j = 0; j < 32; ++j) {
      float4 rv = rs4[j];
      mh0 += DOT4(whA[j], rv);
      mh1 += DOT4(whB[j], rv);
    }
    // ---- reduction window B: 7 independent butterflies ----
    float sMh2  = redsum(mh0 * mh0 + mh1 * mh1);
    float sMhUh = redsum(mh0 * uh0 + mh1 * uh1);
    float sMhBh = redsum(mh0 * bh0 + mh1 * bh1);
    float sUhBh = redsum(uh0 * bh0 + uh1 * bh1);
    float sHMh  = redsum(h0 * mh0 + h1 * mh1);
    float sHUh  = redsum(h0 * uh0 + h1 * uh1);
    float sHBh  = redsum(h0 * bh0 + h1 * bh1);

    // ---- h~ chain ----
    float xnp  = fmaxf(trh, MINN);                 // ||rh|| = trh
    float artp = fatanh(fminf(xnp, ONE_EPS));
    float mhn  = fmaxf(sqrtf(sMh2), MINN);
    float th   = ftanh(mhn * artp * frcp(xnp));
    float shs  = th * frcp(mhn);
    float xyh  = shs * sMhUh;
    float y2h = ynh * ynh, x2h = th * th;
    float c1h = 1.f + 2.f * xyh + y2h, c2h = 1.f - x2h;
    float idnh = frcp(fmaxf(1.f + 2.f * xyh + x2h * y2h, MINN));
    float ah0 = (c1h * shs * mh0 + c2h * uh0) * idnh;
    float ah1 = (c1h * shs * mh1 + c2h * uh1) * idnh;
    float ah2 = fmaxf(idnh * idnh * (c1h * c1h * x2h + 2.f * c1h * c2h * xyh + c2h * c2h * y2h), 0.f);
    float ahb = idnh * (c1h * shs * sMhBh + c2h * sUhBh);
    float hah = idnh * (c1h * shs * sHMh + c2h * sHUh);   // <h, ah>
    float c1hb = 1.f + 2.f * ahb + b2h, c2hb = 1.f - ah2;
    float idnhb = frcp(fmaxf(1.f + 2.f * ahb + ah2 * b2h, MINN));
    float ct0 = (c1hb * ah0 + c2hb * bh0) * idnhb;
    float ct1 = (c1hb * ah1 + c2hb * bh1) * idnhb;
    float ct2 = fmaxf(idnhb * idnhb * (c1hb * c1hb * ah2 + 2.f * c1hb * c2hb * ahb + c2hb * c2hb * b2h), 0.f);
    float hct = idnhb * (c1hb * hah + c2hb * sHBh);       // <h, h_tilde>

    // ---- delta = mobius_add(-h, h_tilde) ----
    float c1d = 1.f - 2.f * hct + ct2, c2d = 1.f - hn2;
    float idnd = frcp(fmaxf(1.f - 2.f * hct + hn2 * ct2, MINN));
    float dl0 = (c2d * ct0 - c1d * h0) * idnd;
    float dl1 = (c2d * ct1 - c1d * h1) * idnd;
    float dn2 = fmaxf(idnd * idnd * (c1d * c1d * hn2 - 2.f * c1d * c2d * hct + c2d * c2d * ct2), 0.f);
    float w0 = dl0 * zg0, w1 = dl1 * zg1;
    // ---- reduction window C: 2 butterflies ----
    float wn2 = redsum(w0 * w0 + w1 * w1);
    float hw  = redsum(h0 * w0 + h1 * w1);

    float dn = fmaxf(sqrtf(dn2), MINN);
    float wn = fmaxf(sqrtf(wn2), MINN);
    float tdd = ftanh(wn * frcp(dn) * fatanh(fminf(dn, ONE_EPS)));
    float szd = tdd * frcp(wn);
    float zd0 = w0 * szd, zd1 = w1 * szd;
    float hzd = hw * szd;
    float t2 = tdd * tdd;
    float c1f = 1.f + 2.f * hzd + t2, c2f = 1.f - hn2;
    float idnf = frcp(fmaxf(1.f + 2.f * hzd + hn2 * t2, MINN));
    float nh0 = (c1f * h0 + c2f * zd0) * idnf;
    float nh1 = (c1f * h1 + c2f * zd1) * idnf;
    hn2 = fmaxf(idnf * idnf * (c1f * c1f * hn2 + 2.f * c1f * c2f * hzd + c2f * c2f * t2), 0.f);
    h0 = nh0; h1 = nh1;
    au0 += m1 * h0; au1 += m1 * h1;
    av0 += m2 * h0; av1 += m2 * h1;
  }
  uarr[b * 128 + l] = au0; uarr[b * 128 + 64 + l] = au1;
  varr[b * 128 + l] = av0; varr[b * 128 + 64 + l] = av1;
}

// ---------------- Kernel D: dist + mobius FF + hyperbolic MLR, 1 wave/b ----
__global__ __launch_bounds__(64) void k_final(
    const float* __restrict__ uarr, const float* __restrict__ varr,
    const float* __restrict__ wfu, const float* __restrict__ wfv,
    const float* __restrict__ bff, const float* __restrict__ bffd,
    const float* __restrict__ wfc, const float* __restrict__ pmlr,
    const float* __restrict__ amlr, const int* __restrict__ cids,
    const float* __restrict__ csemb, float* __restrict__ out) {
  int b = blockIdx.x;
  int l = threadIdx.x;
  __shared__ float us[128], vs[128], cbuf[64];
  float q0 = uarr[b * 128 + l], q1 = uarr[b * 128 + 64 + l];
  float r0 = varr[b * 128 + l], r1 = varr[b * 128 + 64 + l];
  us[l] = q0; us[l + 64] = q1; vs[l] = r0; vs[l + 64] = r1;
  __syncthreads();
  float u2 = redsum(q0 * q0 + q1 * q1);
  float v2 = redsum(r0 * r0 + r1 * r1);
  float uv = redsum(q0 * r0 + q1 * r1);
  // dist(u,v)
  float dsq;
  { float x2 = u2, y2 = v2, xy = -uv;
    float c1 = 1.f + 2.f * xy + y2, c2 = 1.f - x2;
    float idn = 1.f / fmaxf(1.f + 2.f * xy + x2 * y2, MINN);
    float d0 = (c1 * (-q0) + c2 * r0) * idn, d1 = (c1 * (-q1) + c2 * r1) * idn;
    float dn2 = redsum(d0 * d0 + d1 * d1);
    dsq = 2.f * atanhf(clampart(sqrtf(dn2))); }
  // mobius_matvec(W_ff_u, u) and (W_ff_v, v): out dim 64, lane l = row l
  float mxu = 0.f, mxv = 0.f;
  #pragma unroll 4
  for (int jc = 0; jc < 128; jc += 4) {
    float4 uu = *reinterpret_cast<const float4*>(&us[jc]);
    float4 vv = *reinterpret_cast<const float4*>(&vs[jc]);
    float4 wu4 = *reinterpret_cast<const float4*>(wfu + (size_t)l * 128 + jc);
    float4 wv4 = *reinterpret_cast<const float4*>(wfv + (size_t)l * 128 + jc);
    mxu += DOT4(wu4, uu); mxv += DOT4(wv4, vv);
  }
  float xnu = fmaxf(sqrtf(u2), MINN);
  float xnv = fmaxf(sqrtf(v2), MINN);
  float mun = fmaxf(sqrtf(redsum(mxu * mxu)), MINN);
  float mvn = fmaxf(sqrtf(redsum(mxv * mxv)), MINN);
  float tu = tanhf(mun / xnu * atanhf(clampart(xnu)));
  float tv = tanhf(mvn / xnv * atanhf(clampart(xnv)));
  float fu = mxu * (tu / mun), fv = mxv * (tv / mvn);
  // out = mobius_add(fu, fv)
  float o1;
  { float x2 = tu * tu, y2 = tv * tv, xy = redsum(fu * fv);
    float c1 = 1.f + 2.f * xy + y2, c2 = 1.f - x2;
    float idn = 1.f / fmaxf(1.f + 2.f * xy + x2 * y2, MINN);
    o1 = (c1 * fu + c2 * fv) * idn; }
  // out = mobius_add(out, b_ff)
  float bffl = bff[l];
  float bf2 = redsum(bffl * bffl);
  float o2;
  { float x2 = redsum(o1 * o1), y2 = bf2, xy = redsum(o1 * bffl);
    float c1 = 1.f + 2.f * xy + y2, c2 = 1.f - x2;
    float idn = 1.f / fmaxf(1.f + 2.f * xy + x2 * y2, MINN);
    o2 = (c1 * o1 + c2 * bffl) * idn; }
  // mobius_scalar_mul(dsq, b_ff_d)
  float bdl = bffd[l];
  float bdn = fmaxf(sqrtf(redsum(bdl * bdl)), MINN);
  float tsm = tanhf(dsq * atanhf(clampart(bdn)));
  float sm = bdl * (tsm / bdn);
  float o3;
  { float x2 = redsum(o2 * o2), y2 = tsm * tsm, xy = redsum(o2 * sm);
    float c1 = 1.f + 2.f * xy + y2, c2 = 1.f - x2;
    float idn = 1.f / fmaxf(1.f + 2.f * xy + x2 * y2, MINN);
    o3 = (c1 * o2 + c2 * sm) * idn; }
  // mobius_matvec(W_ff_common, common)
  int cid = cids[b];
  float ce = csemb[(size_t)cid * 64 + l];
  cbuf[l] = ce;
  __syncthreads();
  float ce2 = redsum(ce * ce);
  float mxc = 0.f;
  #pragma unroll 4
  for (int jc = 0; jc < 64; jc += 4) {
    float4 cc = *reinterpret_cast<const float4*>(&cbuf[jc]);
    float4 wc4 = *reinterpret_cast<const float4*>(wfc + (size_t)l * 64 + jc);
    mxc += DOT4(wc4, cc);
  }
  float xnc = fmaxf(sqrtf(ce2), MINN);
  float mcn = fmaxf(sqrtf(redsum(mxc * mxc)), MINN);
  float tc = tanhf(mcn / xnc * atanhf(clampart(xnc)));
  float fc = mxc * (tc / mcn);
  float o4;
  { float x2 = redsum(o3 * o3), y2 = tc * tc, xy = redsum(o3 * fc);
    float c1 = 1.f + 2.f * xy + y2, c2 = 1.f - x2;
    float idn = 1.f / fmaxf(1.f + 2.f * xy + x2 * y2, MINN);
    o4 = (c1 * o3 + c2 * fc) * idn; }
  // logmap0 then expmap0
  float on = fmaxf(sqrtf(redsum(o4 * o4)), MINN);
  float lo = o4 * (atanhf(clampart(on)) / on);
  float un = fmaxf(sqrtf(redsum(lo * lo)), MINN);
  float eo = lo * (tanhf(un) / un);
  float eo2 = redsum(eo * eo);
  // hyperbolic MLR
  for (int c = 0; c < 4; ++c) {
    float pc = pmlr[c * 64 + l];
    float ac = amlr[c * 64 + l];
    float p2 = redsum(pc * pc);
    float pe = redsum(pc * eo);
    float x2 = p2, y2 = eo2, xy = -pe;
    float c1 = 1.f + 2.f * xy + y2, c2 = 1.f - x2;
    float idn = 1.f / fmaxf(1.f + 2.f * xy + x2 * y2, MINN);
    float mp = (c1 * (-pc) + c2 * eo) * idn;
    float mp2 = redsum(mp * mp);
    float lam = 2.f / (1.f - mp2);
    float na = sqrtf(redsum(ac * ac));
    float au = ac / fmaxf(na, 1e-12f);
    float pda = redsum(mp * au);
    if (l == 0) out[b * 4 + c] = 2.f * na * asinhf(pda * lam);
  }
}

extern "C" void kernel_launch(void* const* d_in, const int* in_sizes, int n_in,
                              void* d_out, int out_size, void* d_ws, size_t ws_size,
                              hipStream_t stream) {
  const float* seq   = (const float*)d_in[0];
  const float* mask1 = (const float*)d_in[1];
  const float* mask2 = (const float*)d_in[2];
  const int*   cids  = (const int*)d_in[3];
  const float* csemb = (const float*)d_in[4];
  const float* wz  = (const float*)d_in[5];
  const float* wr  = (const float*)d_in[6];
  const float* wh  = (const float*)d_in[7];
  const float* uz  = (const float*)d_in[8];
  const float* ur  = (const float*)d_in[9];
  const float* uh  = (const float*)d_in[10];
  const float* bz  = (const float*)d_in[11];
  const float* br  = (const float*)d_in[12];
  const float* bh  = (const float*)d_in[13];
  const float* wfu = (const float*)d_in[14];
  const float* wfv = (const float*)d_in[15];
  const float* bff = (const float*)d_in[16];
  const float* bffd= (const float*)d_in[17];
  const float* wfc = (const float*)d_in[18];
  const float* pmlr= (const float*)d_in[19];
  const float* amlr= (const float*)d_in[20];
  float* ws = (float*)d_ws;
  float* mx      = ws;                             // 32768*384
  float* a_arr   = mx + (size_t)32768 * 384;       // 32768
  float* xn_arr  = a_arr + 32768;                  // 32768
  float* art_arr = xn_arr + 32768;                 // 32768
  float* yn      = art_arr + 32768;                // 32768*4
  float* ut      = yn + (size_t)32768 * 4;         // 768*384
  float* uarr    = ut + 768 * 384;                 // 256*128
  float* varr    = uarr + 256 * 128;               // 256*128

  k_stats<<<dim3(2048), dim3(256), 0, stream>>>(seq, a_arr, xn_arr, art_arr);
  k_transU<<<dim3(1152), dim3(256), 0, stream>>>(uz, ur, uh, ut);
  k_gemm<<<dim3(256, 3), dim3(256), 0, stream>>>(seq, ut, mx);
  k_mvnl<<<dim3(4096), dim3(256), 0, stream>>>(mx, a_arr, xn_arr, art_arr, yn);
  k_scan<<<dim3(256), dim3(64), 132096, stream>>>(mx, yn, wz, wr, wh, bz, br, bh,
                                                  mask1, mask2, uarr, varr);
  k_final<<<dim3(256), dim3(64), 0, stream>>>(uarr, varr, wfu, wfv, bff, bffd,
                                              wfc, pmlr, amlr, cids, csemb,
                                              (float*)d_out);
}

// Round 3
// 1690.662 us; speedup vs baseline: 1.3300x; 1.0342x over previous
//
#include <hip/hip_runtime.h>
#include <math.h>

#define MINN 1e-15f
#define ONE_EPS 0.99999f   // 1 - 1e-5 (artanh clamp)

// lgkm-only fence: orders LDS ops at compiler level and waits for LDS
// completion WITHOUT draining vmcnt (keeps global prefetches in flight).
// Block = 1 wave, so no s_barrier needed.
#define LDSBAR() asm volatile("s_waitcnt lgkmcnt(0)" ::: "memory")

__device__ __forceinline__ float clampart(float x) {
  return fminf(fmaxf(x, -1.0f + 1e-5f), 1.0f - 1e-5f);
}
__device__ __forceinline__ float redsum(float x) {
  #pragma unroll
  for (int m = 32; m; m >>= 1) x += __shfl_xor(x, m);
  return x;
}
__device__ __forceinline__ float frcp(float x) { return __builtin_amdgcn_rcpf(x); }
__device__ __forceinline__ float fexp2(float x) { return __builtin_amdgcn_exp2f(x); }
__device__ __forceinline__ float flog2(float x) { return __builtin_amdgcn_logf(x); }
// x >= 0
__device__ __forceinline__ float ftanh(float x) {
  float e = fexp2(x * 2.88539008f);          // exp(2x)
  return 1.0f - 2.0f * frcp(e + 1.0f);
}
// 0 <= x < 1
__device__ __forceinline__ float fatanh(float x) {
  return 0.34657359f * flog2((1.0f + x) * frcp(1.0f - x));
}
__device__ __forceinline__ float fsig(float x) {
  return frcp(1.0f + fexp2(-1.44269504f * x));
}
#define DOT4(a, b) ((a).x*(b).x + (a).y*(b).y + (a).z*(b).z + (a).w*(b).w)

// ---------------- Kernel A: per-row stats of sequence (expmap0 scalars) ----
__global__ __launch_bounds__(256) void k_stats(const float* __restrict__ seq,
    float* __restrict__ a_arr, float* __restrict__ xn_arr, float* __restrict__ art_arr) {
  int gw = (blockIdx.x * 256 + threadIdx.x) >> 6;
  int lane = threadIdx.x & 63;
  int nw = (gridDim.x * 256) >> 6;
  for (int r = gw; r < 32768; r += nw) {
    const float* row = seq + (size_t)r * 768;
    float s = 0.f;
    #pragma unroll
    for (int c = 0; c < 3; ++c) {
      float4 v = *reinterpret_cast<const float4*>(row + lane * 4 + c * 256);
      s += v.x*v.x + v.y*v.y + v.z*v.z + v.w*v.w;
    }
    s = redsum(s);
    float un  = sqrtf(s);
    float unc = fmaxf(un, MINN);
    float a   = tanhf(unc) / unc;              // proj = a * seq_row
    float xn  = fmaxf(a * un, MINN);           // ||proj|| clamped
    float art = atanhf(clampart(xn));
    if (lane == 0) { a_arr[r] = a; xn_arr[r] = xn; art_arr[r] = art; }
  }
}

// ---------------- Kernel B0: transpose U matrices into [768][384] ----------
__global__ __launch_bounds__(256) void k_transU(const float* __restrict__ uz,
    const float* __restrict__ ur, const float* __restrict__ uh, float* __restrict__ ut) {
  int idx = blockIdx.x * 256 + threadIdx.x;
  if (idx >= 768 * 384) return;
  int k = idx / 384, n = idx % 384;
  const float* U = (n < 128) ? uz : (n < 256 ? ur : uh);
  int i = n & 127;
  ut[idx] = U[(size_t)i * 768 + k];
}

// ---------------- Kernel B: f32 GEMM  MX = seq[32768x768] @ UT[768x384] ----
#define BM 128
#define BN 128
#define BKK 16
__global__ __launch_bounds__(256) void k_gemm(const float* __restrict__ A,
    const float* __restrict__ Bt, float* __restrict__ C) {
  __shared__ float As[BKK][BM];
  __shared__ float Bs[BKK][BN];
  int t = threadIdx.x;
  int m0 = blockIdx.x * BM;
  int n0 = blockIdx.y * BN;
  int tm = t & 15, tn = t >> 4;
  int arow = t >> 2, acol = (t & 3) * 4;
  int bk = t >> 4, bn = (t & 15) * 8;
  float acc[8][8];
  #pragma unroll
  for (int j = 0; j < 8; ++j)
    #pragma unroll
    for (int jj = 0; jj < 8; ++jj) acc[j][jj] = 0.f;
  for (int k0 = 0; k0 < 768; k0 += BKK) {
    float4 a0 = *reinterpret_cast<const float4*>(A + (size_t)(m0 + arow) * 768 + k0 + acol);
    float4 a1 = *reinterpret_cast<const float4*>(A + (size_t)(m0 + arow + 64) * 768 + k0 + acol);
    float4 b0 = *reinterpret_cast<const float4*>(Bt + (size_t)(k0 + bk) * 384 + n0 + bn);
    float4 b1 = *reinterpret_cast<const float4*>(Bt + (size_t)(k0 + bk) * 384 + n0 + bn + 4);
    __syncthreads();
    As[acol + 0][arow] = a0.x; As[acol + 1][arow] = a0.y;
    As[acol + 2][arow] = a0.z; As[acol + 3][arow] = a0.w;
    As[acol + 0][arow + 64] = a1.x; As[acol + 1][arow + 64] = a1.y;
    As[acol + 2][arow + 64] = a1.z; As[acol + 3][arow + 64] = a1.w;
    *reinterpret_cast<float4*>(&Bs[bk][bn]) = b0;
    *reinterpret_cast<float4*>(&Bs[bk][bn + 4]) = b1;
    __syncthreads();
    #pragma unroll
    for (int k = 0; k < BKK; ++k) {
      float af[8], bf[8];
      #pragma unroll
      for (int j = 0; j < 8; ++j) af[j] = As[k][tm + 16 * j];
      #pragma unroll
      for (int j = 0; j < 8; ++j) bf[j] = Bs[k][tn + 16 * j];
      #pragma unroll
      for (int j = 0; j < 8; ++j)
        #pragma unroll
        for (int jj = 0; jj < 8; ++jj) acc[j][jj] += af[j] * bf[jj];
    }
  }
  #pragma unroll
  for (int j = 0; j < 8; ++j)
    #pragma unroll
    for (int jj = 0; jj < 8; ++jj)
      C[(size_t)(m0 + tm + 16 * j) * 384 + n0 + tn + 16 * jj] = acc[j][jj];
}

// ---------------- Kernel B2: mobius_matvec nonlinearity per (row, gate) ----
__global__ __launch_bounds__(256) void k_mvnl(float* __restrict__ mx,
    const float* __restrict__ a_arr, const float* __restrict__ xn_arr,
    const float* __restrict__ art_arr, float* __restrict__ yn) {
  int gw = (blockIdx.x * 256 + threadIdx.x) >> 6;
  int lane = threadIdx.x & 63;
  int nw = (gridDim.x * 256) >> 6;
  for (int w = gw; w < 32768 * 3; w += nw) {
    int r = w / 3, g = w - r * 3;
    float* p = mx + (size_t)r * 384 + g * 128;
    float2 v = *reinterpret_cast<float2*>(p + lane * 2);
    float a = a_arr[r];
    float x0 = v.x * a, x1 = v.y * a;  // mx = a * raw  (proj @ U.T)
    float s = redsum(x0 * x0 + x1 * x1);
    float mxn = fmaxf(sqrtf(s), MINN);
    float xn = xn_arr[r], art = art_arr[r];
    float tt = tanhf(mxn / xn * art);
    float sc = tt / mxn;
    float2 o; o.x = x0 * sc; o.y = x1 * sc;
    *reinterpret_cast<float2*>(p + lane * 2) = o;
    if (lane == 0) yn[(size_t)r * 4 + g] = tt;   // ||result|| = tt
  }
}

// ---------------- Kernel C: sequential hyperbolic GRU scan, 1 wave per b ---
// wz, wr staged in swizzled LDS (128KB); wh rows in VGPRs (256 regs, no spill
// thanks to __launch_bounds__(64,1)). lgkm-only fences (1-wave block), next-step
// global loads prefetched into registers, pn2 reduction overlapped with the
// h-matvec via unscaled-p trick.
__global__ __launch_bounds__(64, 1) void k_scan(
    const float* __restrict__ ux, const float* __restrict__ yn,
    const float* __restrict__ wz, const float* __restrict__ wr, const float* __restrict__ wh,
    const float* __restrict__ bzp, const float* __restrict__ brp, const float* __restrict__ bhp,
    const float* __restrict__ mask1, const float* __restrict__ mask2,
    float* __restrict__ uarr, float* __restrict__ varr) {
  extern __shared__ __align__(16) float lds[];
  float4* wzs4 = (float4*)lds;            // 4096 float4 = 64KB
  float4* wrs4 = wzs4 + 4096;             // 64KB
  float*  hs   = (float*)(wrs4 + 4096);   // 128 floats
  float*  rs   = hs + 128;                // 128 floats
  float4* hs4  = (float4*)hs;
  float4* rs4  = (float4*)rs;

  int b = blockIdx.x, l = threadIdx.x;
  int sl = l & 31;

  // ---- stage wz, wr into LDS with 32-slot XOR swizzle (bank-balanced) ----
  const float4* wzg = (const float4*)wz;
  const float4* wrg = (const float4*)wr;
  for (int i = l; i < 4096; i += 64) {
    int r = i >> 5, c = i & 31;
    int d = (r << 5) | (c ^ (r & 31));
    wzs4[d] = wzg[i];
    wrs4[d] = wrg[i];
  }
  // ---- wh rows l and l+64 into registers (statically indexed) ----
  const float4* whg = (const float4*)wh;
  float4 whA[32], whB[32];
  #pragma unroll
  for (int j = 0; j < 32; ++j) whA[j] = whg[l * 32 + j];
  #pragma unroll
  for (int j = 0; j < 32; ++j) whB[j] = whg[(l + 64) * 32 + j];

  float bz0 = bzp[l], bz1 = bzp[l + 64];
  float br0 = brp[l], br1 = brp[l + 64];
  float bh0 = bhp[l], bh1 = bhp[l + 64];
  float b2z = redsum(bz0 * bz0 + bz1 * bz1);
  float b2r = redsum(br0 * br0 + br1 * br1);
  float b2h = redsum(bh0 * bh0 + bh1 * bh1);

  float h0 = 0.f, h1 = 0.f, hn2 = 0.f;
  float au0 = 0.f, au1 = 0.f, av0 = 0.f, av1 = 0.f;
  const float*  uxb  = ux + (size_t)b * 128 * 384;
  const float4* ynb4 = (const float4*)yn + (size_t)b * 128;
  const float*  m1p  = mask1 + b * 128;
  const float*  m2p  = mask2 + b * 128;

  // prologue: load t=0 inputs into regs
  float uz0 = uxb[l],       uz1 = uxb[l + 64];
  float ur0 = uxb[128 + l], ur1 = uxb[192 + l];
  float uh0 = uxb[256 + l], uh1 = uxb[320 + l];
  float4 ynt = ynb4[0];
  float m1 = m1p[0], m2 = m2p[0];

  LDSBAR();   // staging writes complete

  for (int t = 0; t < 128; ++t) {
    hs[l] = h0; hs[l + 64] = h1;
    LDSBAR();
    // ---- prefetch step t+1 inputs (hidden under this step's compute) ----
    int tn = (t + 1 < 128) ? t + 1 : 127;
    const float* uxn = uxb + tn * 384;
    float nuz0 = uxn[l],       nuz1 = uxn[l + 64];
    float nur0 = uxn[128 + l], nur1 = uxn[192 + l];
    float nuh0 = uxn[256 + l], nuh1 = uxn[320 + l];
    float4 nyn = ynb4[tn];
    float nm1 = m1p[tn], nm2 = m2p[tn];

    // ---- z/r matvec from LDS ----
    float mz0 = 0.f, mz1 = 0.f, mr0 = 0.f, mr1 = 0.f;
    #pragma unroll
    for (int jc = 0; jc < 32; ++jc) {
      float4 hv = hs4[jc];
      int slot = jc ^ sl;
      float4 a0 = wzs4[(l << 5) | slot];
      float4 a1 = wzs4[((l + 64) << 5) | slot];
      float4 c0 = wrs4[(l << 5) | slot];
      float4 c1 = wrs4[((l + 64) << 5) | slot];
      mz0 += DOT4(a0, hv); mz1 += DOT4(a1, hv);
      mr0 += DOT4(c0, hv); mr1 += DOT4(c1, hv);
    }
    // ---- reduction window A: 8 independent butterflies ----
    float sMz2  = redsum(mz0 * mz0 + mz1 * mz1);
    float sMr2  = redsum(mr0 * mr0 + mr1 * mr1);
    float sMzUz = redsum(mz0 * uz0 + mz1 * uz1);
    float sMrUr = redsum(mr0 * ur0 + mr1 * ur1);
    float sMzBz = redsum(mz0 * bz0 + mz1 * bz1);
    float sMrBr = redsum(mr0 * br0 + mr1 * br1);
    float sUzBz = redsum(uz0 * bz0 + uz1 * bz1);
    float sUrBr = redsum(ur0 * br0 + ur1 * br1);

    float xnh  = fmaxf(sqrtf(hn2), MINN);
    float arth = fatanh(fminf(xnh, ONE_EPS));
    float axr  = arth * frcp(xnh);          // artanh(||h||)/||h||
    float ynz = ynt.x, ynr = ynt.y, ynh = ynt.z;

    // ---- z chain (scalar, analytic norms) ----
    float mzn = fmaxf(sqrtf(sMz2), MINN);
    float tz  = ftanh(mzn * axr);
    float szs = tz * frcp(mzn);
    float xyz = szs * sMzUz;
    float y2z = ynz * ynz, x2z = tz * tz;
    float c1z = 1.f + 2.f * xyz + y2z, c2z = 1.f - x2z;
    float idnz = frcp(fmaxf(1.f + 2.f * xyz + x2z * y2z, MINN));
    float az0 = (c1z * szs * mz0 + c2z * uz0) * idnz;
    float az1 = (c1z * szs * mz1 + c2z * uz1) * idnz;
    float az2 = fmaxf(idnz * idnz * (c1z * c1z * x2z + 2.f * c1z * c2z * xyz + c2z * c2z * y2z), 0.f);
    float azb = idnz * (c1z * szs * sMzBz + c2z * sUzBz);
    float c1zb = 1.f + 2.f * azb + b2z, c2zb = 1.f - az2;
    float idnzb = frcp(fmaxf(1.f + 2.f * azb + az2 * b2z, MINN));
    float cz0 = (c1zb * az0 + c2zb * bz0) * idnzb;
    float cz1 = (c1zb * az1 + c2zb * bz1) * idnzb;
    float cn2z = fmaxf(idnzb * idnzb * (c1zb * c1zb * az2 + 2.f * c1zb * c2zb * azb + c2zb * c2zb * b2z), 0.f);
    float cnz = fmaxf(sqrtf(cn2z), MINN);
    float lsz = fatanh(fminf(cnz, ONE_EPS)) * frcp(cnz);
    float zg0 = fsig(lsz * cz0), zg1 = fsig(lsz * cz1);

    // ---- r chain ----
    float mrn = fmaxf(sqrtf(sMr2), MINN);
    float trr = ftanh(mrn * axr);
    float srs = trr * frcp(mrn);
    float xyr = srs * sMrUr;
    float y2r = ynr * ynr, x2r = trr * trr;
    float c1r = 1.f + 2.f * xyr + y2r, c2r = 1.f - x2r;
    float idnr = frcp(fmaxf(1.f + 2.f * xyr + x2r * y2r, MINN));
    float ar0 = (c1r * srs * mr0 + c2r * ur0) * idnr;
    float ar1 = (c1r * srs * mr1 + c2r * ur1) * idnr;
    float ar2 = fmaxf(idnr * idnr * (c1r * c1r * x2r + 2.f * c1r * c2r * xyr + c2r * c2r * y2r), 0.f);
    float arb = idnr * (c1r * srs * sMrBr + c2r * sUrBr);
    float c1rb = 1.f + 2.f * arb + b2r, c2rb = 1.f - ar2;
    float idnrb = frcp(fmaxf(1.f + 2.f * arb + ar2 * b2r, MINN));
    float cr0 = (c1rb * ar0 + c2rb * br0) * idnrb;
    float cr1 = (c1rb * ar1 + c2rb * br1) * idnrb;
    float cn2r = fmaxf(idnrb * idnrb * (c1rb * c1rb * ar2 + 2.f * c1rb * c2rb * arb + c2rb * c2rb * b2r), 0.f);
    float cnr = fmaxf(sqrtf(cn2r), MINN);
    float lsr = fatanh(fminf(cnr, ONE_EPS)) * frcp(cnr);
    float rg0 = fsig(lsr * cr0), rg1 = fsig(lsr * cr1);

    // ---- rh = mobius_pointwise_mul(h, r): write UNSCALED p, scale later ----
    float p0 = h0 * rg0, p1 = h1 * rg1;
    rs[l] = p0; rs[l + 64] = p1;
    LDSBAR();

    // pn2 reduction overlaps the h-matvec (both in flight on LDS pipe)
    float pn2 = redsum(p0 * p0 + p1 * p1);
    float mh0r = 0.f, mh1r = 0.f;          // W_h · p   (unscaled)
    #pragma unroll
    for (int j = 0; j < 32; ++j) {
      float4 rv = rs4[j];
      mh0r += DOT4(whA[j], rv);
      mh1r += DOT4(whB[j], rv);
    }
    // ---- reduction window B: 6 independent butterflies (raw sums) ----
    float sMh2r  = redsum(mh0r * mh0r + mh1r * mh1r);
    float sMhUhr = redsum(mh0r * uh0 + mh1r * uh1);
    float sMhBhr = redsum(mh0r * bh0 + mh1r * bh1);
    float sHMhr  = redsum(h0 * mh0r + h1 * mh1r);
    float sUhBh  = redsum(uh0 * bh0 + uh1 * bh1);
    float sHUh   = redsum(h0 * uh0 + h1 * uh1);
    float sHBh   = redsum(h0 * bh0 + h1 * bh1);

    // ---- finish rh scaling scalars ----
    float pn  = fmaxf(sqrtf(pn2), MINN);
    float trh = ftanh(pn * axr);
    float srt = trh * frcp(pn);            // rt = srt * p, ||rt|| = trh

    // ---- h~ chain (fold srt into scalars: mh = srt * mh_raw) ----
    float xnp  = fmaxf(trh, MINN);
    float artp = fatanh(fminf(xnp, ONE_EPS));
    float mhn  = fmaxf(srt * sqrtf(sMh2r), MINN);
    float th   = ftanh(mhn * artp * frcp(xnp));
    float g    = th * frcp(mhn) * srt;     // g*mh_raw = (th/mhn)*mh
    float xyh  = g * sMhUhr;
    float y2h = ynh * ynh, x2h = th * th;
    float c1h = 1.f + 2.f * xyh + y2h, c2h = 1.f - x2h;
    float idnh = frcp(fmaxf(1.f + 2.f * xyh + x2h * y2h, MINN));
    float ah0 = (c1h * g * mh0r + c2h * uh0) * idnh;
    float ah1 = (c1h * g * mh1r + c2h * uh1) * idnh;
    float ah2 = fmaxf(idnh * idnh * (c1h * c1h * x2h + 2.f * c1h * c2h * xyh + c2h * c2h * y2h), 0.f);
    float ahb = idnh * (c1h * g * sMhBhr + c2h * sUhBh);
    float hah = idnh * (c1h * g * sHMhr + c2h * sHUh);    // <h, ah>
    float c1hb = 1.f + 2.f * ahb + b2h, c2hb = 1.f - ah2;
    float idnhb = frcp(fmaxf(1.f + 2.f * ahb + ah2 * b2h, MINN));
    float ct0 = (c1hb * ah0 + c2hb * bh0) * idnhb;
    float ct1 = (c1hb * ah1 + c2hb * bh1) * idnhb;
    float ct2 = fmaxf(idnhb * idnhb * (c1hb * c1hb * ah2 + 2.f * c1hb * c2hb * ahb + c2hb * c2hb * b2h), 0.f);
    float hct = idnhb * (c1hb * hah + c2hb * sHBh);       // <h, h_tilde>

    // ---- delta = mobius_add(-h, h_tilde) ----
    float c1d = 1.f - 2.f * hct + ct2, c2d = 1.f - hn2;
    float idnd = frcp(fmaxf(1.f - 2.f * hct + hn2 * ct2, MINN));
    float dl0 = (c2d * ct0 - c1d * h0) * idnd;
    float dl1 = (c2d * ct1 - c1d * h1) * idnd;
    float dn2 = fmaxf(idnd * idnd * (c1d * c1d * hn2 - 2.f * c1d * c2d * hct + c2d * c2d * ct2), 0.f);
    float w0 = dl0 * zg0, w1 = dl1 * zg1;
    // ---- reduction window C: 2 butterflies ----
    float wn2 = redsum(w0 * w0 + w1 * w1);
    float hw  = redsum(h0 * w0 + h1 * w1);

    float dn = fmaxf(sqrtf(dn2), MINN);
    float wn = fmaxf(sqrtf(wn2), MINN);
    float tdd = ftanh(wn * frcp(dn) * fatanh(fminf(dn, ONE_EPS)));
    float szd = tdd * frcp(wn);
    float zd0 = w0 * szd, zd1 = w1 * szd;
    float hzd = hw * szd;
    float t2 = tdd * tdd;
    float c1f = 1.f + 2.f * hzd + t2, c2f = 1.f - hn2;
    float idnf = frcp(fmaxf(1.f + 2.f * hzd + hn2 * t2, MINN));
    float nh0 = (c1f * h0 + c2f * zd0) * idnf;
    float nh1 = (c1f * h1 + c2f * zd1) * idnf;
    hn2 = fmaxf(idnf * idnf * (c1f * c1f * hn2 + 2.f * c1f * c2f * hzd + c2f * c2f * t2), 0.f);
    h0 = nh0; h1 = nh1;
    au0 += m1 * h0; au1 += m1 * h1;
    av0 += m2 * h0; av1 += m2 * h1;

    // ---- rotate prefetched inputs ----
    uz0 = nuz0; uz1 = nuz1; ur0 = nur0; ur1 = nur1; uh0 = nuh0; uh1 = nuh1;
    ynt = nyn; m1 = nm1; m2 = nm2;
  }
  uarr[b * 128 + l] = au0; uarr[b * 128 + 64 + l] = au1;
  varr[b * 128 + l] = av0; varr[b * 128 + 64 + l] = av1;
}

// ---------------- Kernel D: dist + mobius FF + hyperbolic MLR, 1 wave/b ----
__global__ __launch_bounds__(64) void k_final(
    const float* __restrict__ uarr, const float* __restrict__ varr,
    const float* __restrict__ wfu, const float* __restrict__ wfv,
    const float* __restrict__ bff, const float* __restrict__ bffd,
    const float* __restrict__ wfc, const float* __restrict__ pmlr,
    const float* __restrict__ amlr, const int* __restrict__ cids,
    const float* __restrict__ csemb, float* __restrict__ out) {
  int b = blockIdx.x;
  int l = threadIdx.x;
  __shared__ float us[128], vs[128], cbuf[64];
  float q0 = uarr[b * 128 + l], q1 = uarr[b * 128 + 64 + l];
  float r0 = varr[b * 128 + l], r1 = varr[b * 128 + 64 + l];
  us[l] = q0; us[l + 64] = q1; vs[l] = r0; vs[l + 64] = r1;
  __syncthreads();
  float u2 = redsum(q0 * q0 + q1 * q1);
  float v2 = redsum(r0 * r0 + r1 * r1);
  float uv = redsum(q0 * r0 + q1 * r1);
  // dist(u,v)
  float dsq;
  { float x2 = u2, y2 = v2, xy = -uv;
    float c1 = 1.f + 2.f * xy + y2, c2 = 1.f - x2;
    float idn = 1.f / fmaxf(1.f + 2.f * xy + x2 * y2, MINN);
    float d0 = (c1 * (-q0) + c2 * r0) * idn, d1 = (c1 * (-q1) + c2 * r1) * idn;
    float dn2 = redsum(d0 * d0 + d1 * d1);
    dsq = 2.f * atanhf(clampart(sqrtf(dn2))); }
  // mobius_matvec(W_ff_u, u) and (W_ff_v, v): out dim 64, lane l = row l
  float mxu = 0.f, mxv = 0.f;
  #pragma unroll 4
  for (int jc = 0; jc < 128; jc += 4) {
    float4 uu = *reinterpret_cast<const float4*>(&us[jc]);
    float4 vv = *reinterpret_cast<const float4*>(&vs[jc]);
    float4 wu4 = *reinterpret_cast<const float4*>(wfu + (size_t)l * 128 + jc);
    float4 wv4 = *reinterpret_cast<const float4*>(wfv + (size_t)l * 128 + jc);
    mxu += DOT4(wu4, uu); mxv += DOT4(wv4, vv);
  }
  float xnu = fmaxf(sqrtf(u2), MINN);
  float xnv = fmaxf(sqrtf(v2), MINN);
  float mun = fmaxf(sqrtf(redsum(mxu * mxu)), MINN);
  float mvn = fmaxf(sqrtf(redsum(mxv * mxv)), MINN);
  float tu = tanhf(mun / xnu * atanhf(clampart(xnu)));
  float tv = tanhf(mvn / xnv * atanhf(clampart(xnv)));
  float fu = mxu * (tu / mun), fv = mxv * (tv / mvn);
  // out = mobius_add(fu, fv)
  float o1;
  { float x2 = tu * tu, y2 = tv * tv, xy = redsum(fu * fv);
    float c1 = 1.f + 2.f * xy + y2, c2 = 1.f - x2;
    float idn = 1.f / fmaxf(1.f + 2.f * xy + x2 * y2, MINN);
    o1 = (c1 * fu + c2 * fv) * idn; }
  // out = mobius_add(out, b_ff)
  float bffl = bff[l];
  float bf2 = redsum(bffl * bffl);
  float o2;
  { float x2 = redsum(o1 * o1), y2 = bf2, xy = redsum(o1 * bffl);
    float c1 = 1.f + 2.f * xy + y2, c2 = 1.f - x2;
    float idn = 1.f / fmaxf(1.f + 2.f * xy + x2 * y2, MINN);
    o2 = (c1 * o1 + c2 * bffl) * idn; }
  // mobius_scalar_mul(dsq, b_ff_d)
  float bdl = bffd[l];
  float bdn = fmaxf(sqrtf(redsum(bdl * bdl)), MINN);
  float tsm = tanhf(dsq * atanhf(clampart(bdn)));
  float sm = bdl * (tsm / bdn);
  float o3;
  { float x2 = redsum(o2 * o2), y2 = tsm * tsm, xy = redsum(o2 * sm);
    float c1 = 1.f + 2.f * xy + y2, c2 = 1.f - x2;
    float idn = 1.f / fmaxf(1.f + 2.f * xy + x2 * y2, MINN);
    o3 = (c1 * o2 + c2 * sm) * idn; }
  // mobius_matvec(W_ff_common, common)
  int cid = cids[b];
  float ce = csemb[(size_t)cid * 64 + l];
  cbuf[l] = ce;
  __syncthreads();
  float ce2 = redsum(ce * ce);
  float mxc = 0.f;
  #pragma unroll 4
  for (int jc = 0; jc < 64; jc += 4) {
    float4 cc = *reinterpret_cast<const float4*>(&cbuf[jc]);
    float4 wc4 = *reinterpret_cast<const float4*>(wfc + (size_t)l * 64 + jc);
    mxc += DOT4(wc4, cc);
  }
  float xnc = fmaxf(sqrtf(ce2), MINN);
  float mcn = fmaxf(sqrtf(redsum(mxc * mxc)), MINN);
  float tc = tanhf(mcn / xnc * atanhf(clampart(xnc)));
  float fc = mxc * (tc / mcn);
  float o4;
  { float x2 = redsum(o3 * o3), y2 = tc * tc, xy = redsum(o3 * fc);
    float c1 = 1.f + 2.f * xy + y2, c2 = 1.f - x2;
    float idn = 1.f / fmaxf(1.f + 2.f * xy + x2 * y2, MINN);
    o4 = (c1 * o3 + c2 * fc) * idn; }
  // logmap0 then expmap0
  float on = fmaxf(sqrtf(redsum(o4 * o4)), MINN);
  float lo = o4 * (atanhf(clampart(on)) / on);
  float un = fmaxf(sqrtf(redsum(lo * lo)), MINN);
  float eo = lo * (tanhf(un) / un);
  float eo2 = redsum(eo * eo);
  // hyperbolic MLR
  for (int c = 0; c < 4; ++c) {
    float pc = pmlr[c * 64 + l];
    float ac = amlr[c * 64 + l];
    float p2 = redsum(pc * pc);
    float pe = redsum(pc * eo);
    float x2 = p2, y2 = eo2, xy = -pe;
    float c1 = 1.f + 2.f * xy + y2, c2 = 1.f - x2;
    float idn = 1.f / fmaxf(1.f + 2.f * xy + x2 * y2, MINN);
    float mp = (c1 * (-pc) + c2 * eo) * idn;
    float mp2 = redsum(mp * mp);
    float lam = 2.f / (1.f - mp2);
    float na = sqrtf(redsum(ac * ac));
    float au = ac / fmaxf(na, 1e-12f);
    float pda = redsum(mp * au);
    if (l == 0) out[b * 4 + c] = 2.f * na * asinhf(pda * lam);
  }
}

extern "C" void kernel_launch(void* const* d_in, const int* in_sizes, int n_in,
                              void* d_out, int out_size, void* d_ws, size_t ws_size,
                              hipStream_t stream) {
  const float* seq   = (const float*)d_in[0];
  const float* mask1 = (const float*)d_in[1];
  const float* mask2 = (const float*)d_in[2];
  const int*   cids  = (const int*)d_in[3];
  const float* csemb = (const float*)d_in[4];
  const float* wz  = (const float*)d_in[5];
  const float* wr  = (const float*)d_in[6];
  const float* wh  = (const float*)d_in[7];
  const float* uz  = (const float*)d_in[8];
  const float* ur  = (const float*)d_in[9];
  const float* uh  = (const float*)d_in[10];
  const float* bz  = (const float*)d_in[11];
  const float* br  = (const float*)d_in[12];
  const float* bh  = (const float*)d_in[13];
  const float* wfu = (const float*)d_in[14];
  const float* wfv = (const float*)d_in[15];
  const float* bff = (const float*)d_in[16];
  const float* bffd= (const float*)d_in[17];
  const float* wfc = (const float*)d_in[18];
  const float* pmlr= (const float*)d_in[19];
  const float* amlr= (const float*)d_in[20];
  float* ws = (float*)d_ws;
  float* mx      = ws;                             // 32768*384
  float* a_arr   = mx + (size_t)32768 * 384;       // 32768
  float* xn_arr  = a_arr + 32768;                  // 32768
  float* art_arr = xn_arr + 32768;                 // 32768
  float* yn      = art_arr + 32768;                // 32768*4
  float* ut      = yn + (size_t)32768 * 4;         // 768*384
  float* uarr    = ut + 768 * 384;                 // 256*128
  float* varr    = uarr + 256 * 128;               // 256*128

  k_stats<<<dim3(2048), dim3(256), 0, stream>>>(seq, a_arr, xn_arr, art_arr);
  k_transU<<<dim3(1152), dim3(256), 0, stream>>>(uz, ur, uh, ut);
  k_gemm<<<dim3(256, 3), dim3(256), 0, stream>>>(seq, ut, mx);
  k_mvnl<<<dim3(4096), dim3(256), 0, stream>>>(mx, a_arr, xn_arr, art_arr, yn);
  k_scan<<<dim3(256), dim3(64), 132096, stream>>>(mx, yn, wz, wr, wh, bz, br, bh,
                                                  mask1, mask2, uarr, varr);
  k_final<<<dim3(256), dim3(64), 0, stream>>>(uarr, varr, wfu, wfv, bff, bffd,
                                              wfc, pmlr, amlr, cids, csemb,
                                              (float*)d_out);
}